// Round 4
// baseline (26.061 us; speedup 1.0000x reference)
//
#include <hip/hip_runtime.h>

// SpodNet: per-batch sequential column sweep (B=16384 independent 22x22 fp32).
// Output Theta never depends on W; per batch, for c = 0..21:
//   v' = Wcol @ (row c minus elem c); row/col c <- v' symmetrically.
// Round 4: round-3's 2-deep counted-vmcnt pipeline with the ISSUE-ORDER BUG
// fixed: Wcol vector loads are issued FIRST (they are per-lane vm ops; in
// round 3 they were issued last, so vmcnt(16) counted THEM as the 16
// outstanding and silently drained tile B -> fully serialized pipeline).
// sched_barrier(0) pins each vm-issue cluster so FIFO vmcnt counting holds.

#define PP 22
#define PM 21
#define MAT 484                        // floats per matrix
#define TB 8                           // matrices per tile (one wave, 8 lanes each)
#define TILE_FLOATS (TB * MAT)         // 3872
#define TILE_BYTES  (TILE_FLOATS * 4)  // 15488

typedef const __attribute__((address_space(1))) void* gas_ptr;
typedef __attribute__((address_space(3))) void* las_ptr;

__device__ __forceinline__ void stage_tile(const float* __restrict__ gsrc,
                                           float* lbuf, int lane)
{
    // 16 vm ops: 15 x 1024 B + 128 B tail (lanes 0..7)
    const char* src = (const char*)gsrc;
    #pragma unroll
    for (int it = 0; it < 15; ++it) {
        __builtin_amdgcn_global_load_lds(
            (gas_ptr)(src + it * 1024 + lane * 16),
            (las_ptr)((char*)lbuf + it * 1024), 16, 0, 0);
    }
    if (lane < 8) {
        __builtin_amdgcn_global_load_lds(
            (gas_ptr)(src + 15360 + lane * 16),
            (las_ptr)((char*)lbuf + 15360), 16, 0, 0);
    }
}

__device__ __forceinline__ void store_tile(const float* lbuf,
                                           float* __restrict__ gdst, int lane)
{
    // 16 vm stores: 968 float4 = 15*64 + 8
    const float4* l4 = reinterpret_cast<const float4*>(lbuf);
    float4* g4 = reinterpret_cast<float4*>(gdst);
    #pragma unroll
    for (int it = 0; it < 15; ++it)
        g4[it * 64 + lane] = l4[it * 64 + lane];
    if (lane < 8)
        g4[960 + lane] = l4[960 + lane];
}

__device__ __forceinline__ void sweep_tile(float* M, int k,
                                           const float* w0, const float* w1,
                                           const float* w2)
{
    #pragma unroll
    for (int c = 0; c < PP; ++c) {
        float f[PP];
        {
            const float2* row = reinterpret_cast<const float2*>(&M[c * PP]);
            #pragma unroll
            for (int h = 0; h < 11; ++h) {
                float2 t = row[h];
                f[2 * h]     = t.x;
                f[2 * h + 1] = t.y;
            }
        }

        float a0 = 0.f, a1 = 0.f, a2 = 0.f;
        float b0a = 0.f, b1a = 0.f, b2a = 0.f;
        #pragma unroll
        for (int j = 0; j < PM; ++j) {
            const int mj = j + (j >= c ? 1 : 0);   // compile-time (full unroll)
            if (j < 11) {
                a0 = fmaf(w0[j], f[mj], a0);
                a1 = fmaf(w1[j], f[mj], a1);
                a2 = fmaf(w2[j], f[mj], a2);
            } else {
                b0a = fmaf(w0[j], f[mj], b0a);
                b1a = fmaf(w1[j], f[mj], b1a);
                b2a = fmaf(w2[j], f[mj], b2a);
            }
        }
        a0 += b0a; a1 += b1a; a2 += b2a;

        // column writes [mi, c]: read later (step mi) or final
        const int mi0 = k      + (k      >= c ? 1 : 0);
        const int mi1 = k + 8  + (k + 8  >= c ? 1 : 0);
        const int mi2 = k + 16 + (k + 16 >= c ? 1 : 0);
        M[mi0 * PP + c] = a0;
        M[mi1 * PP + c] = a1;
        if (k < 5) M[mi2 * PP + c] = a2;
        // row writes [c, mi]: only mi < c are final (mi > c overwritten at
        // step mi before any read -> dead, skip)
        if (mi0 < c) M[c * PP + mi0] = a0;
        if (mi1 < c) M[c * PP + mi1] = a1;
        if (k < 5 && mi2 < c) M[c * PP + mi2] = a2;
    }
}

__global__ __launch_bounds__(64)
void spodnet_sweep(const float* __restrict__ theta_in,
                   const float* __restrict__ wcol,
                   float* __restrict__ theta_out)
{
    __shared__ float lds[2][TILE_FLOATS];   // 30976 B -> 4 blocks/CU at grid 1024
    const int lane = threadIdx.x;
    const int g = lane >> 3;                // matrix within tile
    const int k = lane & 7;                 // lane within 8-lane group

    const long t0 = (long)blockIdx.x * 2;
    const float* ginA = theta_in  + t0 * TILE_FLOATS;
    const float* ginB = ginA + TILE_FLOATS;
    float* goutA = theta_out + t0 * TILE_FLOATS;
    float* goutB = goutA + TILE_FLOATS;

    // ---- (1) Wcol rows FIRST: these are per-lane vector loads (vm ops).
    // They must be OLDER than both glds clusters for the vmcnt(16) FIFO
    // counting below to be correct.
    float w0[PM], w1[PM], w2[PM];
    {
        const int r0 = k, r1 = k + 8, r2 = (k < 5) ? (k + 16) : 20;
        #pragma unroll
        for (int j = 0; j < PM; ++j) {
            w0[j] = wcol[r0 * PM + j];
            w1[j] = wcol[r1 * PM + j];
            w2[j] = wcol[r2 * PM + j];
        }
    }
    __builtin_amdgcn_sched_barrier(0);   // pin: wcol loads issued before glds A

    // ---- (2) stage A, then (3) stage B; pinned so clusters don't interleave
    stage_tile(ginA, lds[0], lane);
    __builtin_amdgcn_sched_barrier(0);   // pin: all of A before any of B
    stage_tile(ginB, lds[1], lane);
    __builtin_amdgcn_sched_barrier(0);

    // wait: drains wcol + tile A (FIFO: the 16 newest = tile B, stays in flight)
    asm volatile("s_waitcnt vmcnt(16)" ::: "memory");
    __builtin_amdgcn_sched_barrier(0);

    sweep_tile(&lds[0][g * MAT], k, w0, w1, w2);
    store_tile(lds[0], goutA, lane);     // 16 vm stores issued
    __builtin_amdgcn_sched_barrier(0);

    // wait: outstanding = B(16) + storeA(16); drains B, storeA stays in flight
    asm volatile("s_waitcnt vmcnt(16)" ::: "memory");
    __builtin_amdgcn_sched_barrier(0);

    sweep_tile(&lds[1][g * MAT], k, w0, w1, w2);
    store_tile(lds[1], goutB, lane);
}

extern "C" void kernel_launch(void* const* d_in, const int* in_sizes, int n_in,
                              void* d_out, int out_size, void* d_ws, size_t ws_size,
                              hipStream_t stream) {
    const float* theta = (const float*)d_in[0];
    const float* wcol  = (const float*)d_in[1];
    float* out = (float*)d_out;

    const int Btot = in_sizes[0] / (PP * PP);   // 16384
    const int grid = Btot / (TB * 2);           // 1024 blocks, 2 tiles each
    hipLaunchKernelGGL(spodnet_sweep, dim3(grid), dim3(64), 0, stream,
                       theta, wcol, out);
}

// Round 6
// 17.735 us; speedup vs baseline: 1.4695x; 1.4695x over previous
//
#include <hip/hip_runtime.h>

// SpodNet: per-batch sequential column sweep (B=16384 independent 22x22 fp32).
// Output Theta never depends on W; per batch, for c = 0..21:
//   v' = Wcol @ (row c minus elem c); row/col c <- v' symmetrically.
// Round 6: round-5 kernel with the compile fix -- nontemporal stores use a
// native clang ext_vector float4 (HIP's float4 class is rejected by
// __builtin_nontemporal_store). Column loop software-pipelined: prefetch row
// c+1 during column c's FMAs (only word (c+1,c) is stale; patched after the
// writes, its 3 FMAs scheduled last in column c+1).

#define PP 22
#define PM 21
#define MAT 484                        // floats per matrix
#define TB 8                           // matrices per tile (one wave, 8 lanes each)
#define TILE_FLOATS (TB * MAT)         // 3872 floats = 15488 B

typedef const __attribute__((address_space(1))) void* gas_ptr;
typedef __attribute__((address_space(3))) void* las_ptr;
typedef float f32x4 __attribute__((ext_vector_type(4)));
typedef float f32x2 __attribute__((ext_vector_type(2)));

__global__ __launch_bounds__(64)
void spodnet_sweep(const float* __restrict__ theta_in,
                   const float* __restrict__ wcol,
                   float* __restrict__ theta_out)
{
    __shared__ float lds[TILE_FLOATS];   // linear (glds destination)
    const int lane = threadIdx.x;
    const int g = lane >> 3;             // matrix within tile
    const int k = lane & 7;              // lane within 8-lane group

    const float* gin  = theta_in  + (long)blockIdx.x * TILE_FLOATS;
    float*       gout = theta_out + (long)blockIdx.x * TILE_FLOATS;

    // ---- async stage: global -> LDS, 16 vm ops ----
    {
        const char* src = (const char*)gin;
        #pragma unroll
        for (int it = 0; it < 15; ++it) {
            __builtin_amdgcn_global_load_lds(
                (gas_ptr)(src + it * 1024 + lane * 16),
                (las_ptr)((char*)lds + it * 1024), 16, 0, 0);
        }
        if (lane < 8) {
            __builtin_amdgcn_global_load_lds(
                (gas_ptr)(src + 15360 + lane * 16),
                (las_ptr)((char*)lds + 15360), 16, 0, 0);
        }
    }

    // ---- Wcol rows k, k+8, k+16 (clamped; k>=5 never uses the 3rd result) ----
    float w0[PM], w1[PM], w2[PM];
    {
        const int r0 = k, r1 = k + 8, r2 = (k < 5) ? (k + 16) : 20;
        #pragma unroll
        for (int j = 0; j < PM; ++j) {
            w0[j] = wcol[r0 * PM + j];
            w1[j] = wcol[r1 * PM + j];
            w2[j] = wcol[r2 * PM + j];
        }
    }

    asm volatile("s_waitcnt vmcnt(0)" ::: "memory");
    __builtin_amdgcn_sched_barrier(0);

    float* M = &lds[g * MAT];

    // ---- pipelined column sweep (fully unrolled, all indices static) ----
    float fb[2][PP];   // fb[c&1] = row c
    {
        const f32x2* row = reinterpret_cast<const f32x2*>(&M[0]);
        #pragma unroll
        for (int h = 0; h < 11; ++h) {
            f32x2 t = row[h];
            fb[0][2 * h] = t.x; fb[0][2 * h + 1] = t.y;
        }
    }

    #pragma unroll
    for (int c = 0; c < PP; ++c) {
        const int cur = c & 1, nxt = cur ^ 1;

        // early prefetch of row c+1: only word (c+1,c) is stale (patched below)
        if (c < PP - 1) {
            const f32x2* row = reinterpret_cast<const f32x2*>(&M[(c + 1) * PP]);
            #pragma unroll
            for (int h = 0; h < 11; ++h) {
                f32x2 t = row[h];
                fb[nxt][2 * h] = t.x; fb[nxt][2 * h + 1] = t.y;
            }
        }

        // FMAs over j != c-1 (two partial chains), fresh term j = c-1 last
        float a0 = 0.f, a1 = 0.f, a2 = 0.f;
        float p0 = 0.f, p1 = 0.f, p2 = 0.f;
        int cnt = 0;
        #pragma unroll
        for (int j = 0; j < PM; ++j) {
            if (j == c - 1) continue;              // compile-time skip
            const int mj = j + (j >= c ? 1 : 0);   // compile-time
            const float fv = fb[cur][mj];
            if ((cnt & 1) == 0) {
                a0 = fmaf(w0[j], fv, a0);
                a1 = fmaf(w1[j], fv, a1);
                a2 = fmaf(w2[j], fv, a2);
            } else {
                p0 = fmaf(w0[j], fv, p0);
                p1 = fmaf(w1[j], fv, p1);
                p2 = fmaf(w2[j], fv, p2);
            }
            ++cnt;
        }
        a0 += p0; a1 += p1; a2 += p2;
        if (c >= 1) {                              // fresh value (c, c-1), mj = c-1
            const float fv = fb[cur][c - 1];
            a0 = fmaf(w0[c - 1], fv, a0);
            a1 = fmaf(w1[c - 1], fv, a1);
            a2 = fmaf(w2[c - 1], fv, a2);
        }

        // column writes [mi, c]: re-read at step mi, or final
        const int mi0 = k      + (k      >= c ? 1 : 0);
        const int mi1 = k + 8  + (k + 8  >= c ? 1 : 0);
        const int mi2 = k + 16 + (k + 16 >= c ? 1 : 0);
        M[mi0 * PP + c] = a0;
        M[mi1 * PP + c] = a1;
        if (k < 5) M[mi2 * PP + c] = a2;
        // row writes [c, mi]: only mi < c are final (mi > c are dead)
        if (mi0 < c) M[c * PP + mi0] = a0;
        if (mi1 < c) M[c * PP + mi1] = a1;
        if (k < 5 && mi2 < c) M[c * PP + mi2] = a2;

        // patch the one fresh word of row c+1: (c+1, c), just written above
        if (c < PP - 1)
            fb[nxt][c] = M[(c + 1) * PP + c];
    }

    // ---- store: LDS -> global, nontemporal float4 (native clang vector) ----
    {
        const f32x4* l4 = reinterpret_cast<const f32x4*>(lds);
        f32x4* g4 = reinterpret_cast<f32x4*>(gout);
        #pragma unroll
        for (int it = 0; it < 15; ++it)
            __builtin_nontemporal_store(l4[it * 64 + lane], &g4[it * 64 + lane]);
        if (lane < 8)
            __builtin_nontemporal_store(l4[960 + lane], &g4[960 + lane]);
    }
}

extern "C" void kernel_launch(void* const* d_in, const int* in_sizes, int n_in,
                              void* d_out, int out_size, void* d_ws, size_t ws_size,
                              hipStream_t stream) {
    const float* theta = (const float*)d_in[0];
    const float* wcol  = (const float*)d_in[1];
    float* out = (float*)d_out;

    const int Btot = in_sizes[0] / (PP * PP);   // 16384
    const int grid = Btot / TB;                 // 2048 blocks, 8 waves/CU
    hipLaunchKernelGGL(spodnet_sweep, dim3(grid), dim3(64), 0, stream,
                       theta, wcol, out);
}